// Round 11
// baseline (300.382 us; speedup 1.0000x reference)
//
#include <hip/hip_runtime.h>
#include <hip/hip_bf16.h>

namespace {

constexpr float kAlpha = 0.025f;
constexpr float kC1 = 1.0e-4f;  // (0.01*1)^2
constexpr float kC2 = 9.0e-4f;  // (0.03*1)^2

constexpr int MPS = 68;  // mp row stride (shorts): 136 B, b64-aligned rows
constexpr int HTS = 68;  // hbT col stride (shorts): 136 B, b64-aligned

typedef __attribute__((ext_vector_type(8))) short short8;
typedef __attribute__((ext_vector_type(4))) float f32x4;

// LDS: union(mp 17.4 KB, hbT 52.2 KB) + red = 52.3 KB -> 3 blocks/CU
// group1 planes: sigma s in {0,1,2}, map m -> plane s*4+m  (12 planes)
// group2 planes: sigma 3 map m -> plane m; sigma 4 map m -> plane 4+m; d -> 8
struct __align__(16) Smem {
  union {
    short mp[2][64 * MPS];    // bf16 pixel maps: x, y (staging only)
    short hbT[12][32 * HTS];  // bf16 H results, transposed [out_col][row]
  };
  float red[4];
};

union Frag {
  int i[4];
  short8 s8;
};

__device__ __forceinline__ unsigned f2bf(float f) {  // RNE fp32 -> bf16 bits
  unsigned u = __float_as_uint(f);
  return (u + 0x7FFFu + ((u >> 16) & 1u)) >> 16;
}
__device__ __forceinline__ unsigned pk(float a, float b) {  // packed cvt (RNE)
  union {
    __hip_bfloat162 h;
    unsigned u;
  } c;
  c.h = __float22bfloat162_rn(make_float2(a, b));
  return c.u;
}
__device__ __forceinline__ float bfl(unsigned u) {
  return __uint_as_float(u << 16);
}
__device__ __forceinline__ float bfh(unsigned u) {
  return __uint_as_float(u & 0xFFFF0000u);
}
__device__ __forceinline__ float frcp(float x) {  // v_rcp_f32, ~1 ulp
  return __builtin_amdgcn_rcpf(x);
}

// W fragment via lane shuffles: element (p,h) = g[k - n],
// k = kt*32 + quad*8 + 2p+h, n = nt*16 + l16; lanes >= 33 hold 0 and the
// &63 wrap maps every out-of-band index onto a zero lane. Symmetric for
// A-operand (V pass) and B-operand (H pass) layouts.
__device__ __forceinline__ short8 wbuild(unsigned tb, int lane, int nt,
                                         int kt) {
  const int b0 = (lane >> 4) * 8 - (lane & 15) + 32 * kt - 16 * nt;
  Frag u;
#pragma unroll
  for (int p = 0; p < 4; ++p) {
    unsigned lo = (unsigned)__shfl((int)tb, (b0 + 2 * p) & 63, 64);
    unsigned hi = (unsigned)__shfl((int)tb, (b0 + 2 * p + 1) & 63, 64);
    u.i[p] = (int)(lo | (hi << 16));
  }
  return u.s8;
}

__device__ __forceinline__ void load_xy(const Smem& sm, int row, int quad,
                                        Frag fx[2], Frag fy[2]) {
  const short* px = &sm.mp[0][row * MPS + quad * 8];
  const short* py = &sm.mp[1][row * MPS + quad * 8];
  *(int2*)&fx[0].i[0] = *(const int2*)(px);
  *(int2*)&fx[0].i[2] = *(const int2*)(px + 4);
  *(int2*)&fx[1].i[0] = *(const int2*)(px + 32);
  *(int2*)&fx[1].i[2] = *(const int2*)(px + 36);
  *(int2*)&fy[0].i[0] = *(const int2*)(py);
  *(int2*)&fy[0].i[2] = *(const int2*)(py + 4);
  *(int2*)&fy[1].i[0] = *(const int2*)(py + 32);
  *(int2*)&fy[1].i[2] = *(const int2*)(py + 36);
}

__global__ __launch_bounds__(256, 2) void msssim_l1_kernel(
    const float* __restrict__ x, const float* __restrict__ y,
    const float* __restrict__ gm, float* __restrict__ out) {
  __shared__ Smem sm;
  const int tid = threadIdx.x;
  const int lane = tid & 63;
  const int w = tid >> 6;
  const int quad = lane >> 4;
  const int l16 = lane & 15;

  // per-lane taps (lane j<33 holds m[16][j]); per-sigma bf16 tap bits
  float traw[5];
#pragma unroll
  for (int s = 0; s < 5; ++s)
    traw[s] = (lane < 33) ? gm[s * 1089 + 16 * 33 + lane] : 0.f;
  unsigned tbs[5];
#pragma unroll
  for (int s = 0; s < 5; ++s)
    tbs[s] = f2bf(traw[s] * rsqrtf(__shfl(traw[s], 16, 64)));
  float corr;  // fp32/bf16 tap-sum compensation for the l1 conv (sigma 4)
  {
    float g = traw[4] * rsqrtf(__shfl(traw[4], 16, 64));
    float se = g, st = bfl(f2bf(g));
#pragma unroll
    for (int off = 32; off > 0; off >>= 1) {
      se += __shfl_xor(se, off, 64);
      st += __shfl_xor(st, off, 64);
    }
    float r1 = se / st;
    corr = r1 * r1;
  }

  // 64x64 halo patch, zero-padded; bf16 x/y maps in LDS (mp region)
  const float* xb = x + blockIdx.z * (512 * 512);
  const float* yb = y + blockIdx.z * (512 * 512);
  const int rb = blockIdx.y * 32 - 16;
  const int cb = blockIdx.x * 32 - 16;
  for (int f = tid; f < 1024; f += 256) {
    int pr = f >> 4;
    int pc = (f & 15) << 2;
    int gr = rb + pr, gc = cb + pc;
    float4 vx = make_float4(0.f, 0.f, 0.f, 0.f);
    float4 vy = vx;
    if (gr >= 0 && gr < 512 && gc >= 0 && gc < 512) {
      vx = *(const float4*)(xb + gr * 512 + gc);
      vy = *(const float4*)(yb + gr * 512 + gc);
    }
    const int base = pr * MPS + pc;
    *(int2*)(&sm.mp[0][base]) =
        make_int2((int)pk(vx.x, vx.y), (int)pk(vx.z, vx.w));
    *(int2*)(&sm.mp[1][base]) =
        make_int2((int)pk(vy.x, vy.y), (int)pk(vy.z, vy.w));
  }
  __syncthreads();  // B1: patch ready

  // persistent A-fragments for THIS wave's map (m = w), all 4 row tiles;
  // every wave also builds |x-y| fragments for ITS OWN mtile (mt == w)
  Frag A[4][2];
  Frag dA[2];
#pragma unroll
  for (int mt = 0; mt < 4; ++mt) {
    Frag fx[2], fy[2];
    load_xy(sm, mt * 16 + l16, quad, fx, fy);
    if (mt == w) {  // own-mtile |x-y| fragments (plane 8, balanced)
#pragma unroll
      for (int h = 0; h < 2; ++h)
#pragma unroll
        for (int i = 0; i < 4; ++i) {
          unsigned ux = (unsigned)fx[h].i[i], uy = (unsigned)fy[h].i[i];
          dA[h].i[i] = (int)pk(fabsf(bfl(ux) - bfl(uy)),
                               fabsf(bfh(ux) - bfh(uy)));
        }
    }
    if (w == 0) {
      A[mt][0] = fx[0];
      A[mt][1] = fx[1];
    } else if (w == 1) {
      A[mt][0] = fy[0];
      A[mt][1] = fy[1];
    } else {
#pragma unroll
      for (int h = 0; h < 2; ++h)
#pragma unroll
        for (int i = 0; i < 4; ++i) {
          unsigned ux = (unsigned)fx[h].i[i], uy = (unsigned)fy[h].i[i];
          float xl = bfl(ux), xh = bfh(ux), yl = bfl(uy), yh = bfh(uy);
          A[mt][h].i[i] = (w == 2) ? (int)pk(fmaf(xl, xl, yl * yl),
                                            fmaf(xh, xh, yh * yh))
                                   : (int)pk(xl * yl, xh * yh);
        }
    }
  }
  __syncthreads();  // B2: all mp reads done -> hbT may overwrite the union

  const int mtv = w >> 1, ntv = w & 1;
  f32x4 Pcs = {1.f, 1.f, 1.f, 1.f};
  f32x4 lumP = {0.f, 0.f, 0.f, 0.f};
  f32x4 l1v = {0.f, 0.f, 0.f, 0.f};

  // ================= group 1: sigmas 0..2 =================
  {
    short8 wf[3][2][2];  // kept alive through V: V's A-operand = wf[s][mtv][kt]
#pragma unroll
    for (int s = 0; s < 3; ++s)
#pragma unroll
      for (int nt = 0; nt < 2; ++nt)
#pragma unroll
        for (int kt = 0; kt < 2; ++kt)
          wf[s][nt][kt] = wbuild(tbs[s], lane, nt, kt);

#pragma unroll
    for (int s = 0; s < 3; ++s)  // H: wave w = map w, plane s*4+w
#pragma unroll
      for (int mt = 0; mt < 4; ++mt)
#pragma unroll
        for (int nt = 0; nt < 2; ++nt) {
          f32x4 acc = {0.f, 0.f, 0.f, 0.f};
          acc = __builtin_amdgcn_mfma_f32_16x16x32_bf16(A[mt][0].s8,
                                                        wf[s][nt][0], acc, 0,
                                                        0, 0);
          acc = __builtin_amdgcn_mfma_f32_16x16x32_bf16(A[mt][1].s8,
                                                        wf[s][nt][1], acc, 0,
                                                        0, 0);
          *(int2*)(&sm.hbT[s * 4 + w][(nt * 16 + l16) * HTS + mt * 16 +
                                      quad * 4]) =
              make_int2((int)pk(acc[0], acc[1]), (int)pk(acc[2], acc[3]));
        }
    __syncthreads();  // B3: group-1 hbT ready

#pragma unroll
    for (int s = 0; s < 3; ++s) {  // V + combine: wave = output quadrant
      f32x4 va[4];
#pragma unroll
      for (int m = 0; m < 4; ++m) {
        const short* bp = &sm.hbT[s * 4 + m][(ntv * 16 + l16) * HTS + quad * 8];
        Frag b0, b1;
        *(int2*)&b0.i[0] = *(const int2*)(bp);
        *(int2*)&b0.i[2] = *(const int2*)(bp + 4);
        *(int2*)&b1.i[0] = *(const int2*)(bp + 32);
        *(int2*)&b1.i[2] = *(const int2*)(bp + 36);
        f32x4 acc = {0.f, 0.f, 0.f, 0.f};
        acc = __builtin_amdgcn_mfma_f32_16x16x32_bf16(wf[s][mtv][0], b0.s8,
                                                      acc, 0, 0, 0);
        acc = __builtin_amdgcn_mfma_f32_16x16x32_bf16(wf[s][mtv][1], b1.s8,
                                                      acc, 0, 0, 0);
        va[m] = acc;
      }
#pragma unroll
      for (int r = 0; r < 4; ++r) {
        float mux = va[0][r], muy = va[1][r], m2 = va[2][r], mxy = va[3][r];
        float cs = (2.f * (mxy - mux * muy) + kC2) *
                   frcp((m2 - mux * mux - muy * muy) + kC2);
        Pcs[r] *= cs;
      }
    }
  }
  __syncthreads();  // B4: group-1 V reads done, hbT reusable

  // ================= group 2: sigmas 3,4 =================
  {
    short8 wf[2][2][2];
#pragma unroll
    for (int s = 0; s < 2; ++s)
#pragma unroll
      for (int nt = 0; nt < 2; ++nt)
#pragma unroll
        for (int kt = 0; kt < 2; ++kt)
          wf[s][nt][kt] = wbuild(tbs[3 + s], lane, nt, kt);

#pragma unroll
    for (int s = 0; s < 2; ++s) {  // H: planes s? -> pb + w
      const int pb = (s == 0) ? 0 : 4;
#pragma unroll
      for (int mt = 0; mt < 4; ++mt)
#pragma unroll
        for (int nt = 0; nt < 2; ++nt) {
          f32x4 acc = {0.f, 0.f, 0.f, 0.f};
          acc = __builtin_amdgcn_mfma_f32_16x16x32_bf16(A[mt][0].s8,
                                                        wf[s][nt][0], acc, 0,
                                                        0, 0);
          acc = __builtin_amdgcn_mfma_f32_16x16x32_bf16(A[mt][1].s8,
                                                        wf[s][nt][1], acc, 0,
                                                        0, 0);
          *(int2*)(&sm.hbT[pb + w][(nt * 16 + l16) * HTS + mt * 16 +
                                   quad * 4]) =
              make_int2((int)pk(acc[0], acc[1]), (int)pk(acc[2], acc[3]));
        }
    }
    // plane 8 (sigma-4 |x-y|): each wave computes ITS mtile (mt = w)
#pragma unroll
    for (int nt = 0; nt < 2; ++nt) {
      f32x4 acc = {0.f, 0.f, 0.f, 0.f};
      acc = __builtin_amdgcn_mfma_f32_16x16x32_bf16(dA[0].s8, wf[1][nt][0],
                                                    acc, 0, 0, 0);
      acc = __builtin_amdgcn_mfma_f32_16x16x32_bf16(dA[1].s8, wf[1][nt][1],
                                                    acc, 0, 0, 0);
      *(int2*)(&sm.hbT[8][(nt * 16 + l16) * HTS + w * 16 + quad * 4]) =
          make_int2((int)pk(acc[0], acc[1]), (int)pk(acc[2], acc[3]));
    }
    __syncthreads();  // B5: group-2 hbT ready

#pragma unroll
    for (int s = 0; s < 2; ++s) {
      const int pb = (s == 0) ? 0 : 4;
      const int nm = (s == 0) ? 4 : 5;
      f32x4 va[5];
#pragma unroll
      for (int m = 0; m < 5; ++m) {
        if (m >= nm) continue;
        const int plane = (m == 4) ? 8 : pb + m;
        const short* bp = &sm.hbT[plane][(ntv * 16 + l16) * HTS + quad * 8];
        Frag b0, b1;
        *(int2*)&b0.i[0] = *(const int2*)(bp);
        *(int2*)&b0.i[2] = *(const int2*)(bp + 4);
        *(int2*)&b1.i[0] = *(const int2*)(bp + 32);
        *(int2*)&b1.i[2] = *(const int2*)(bp + 36);
        f32x4 acc = {0.f, 0.f, 0.f, 0.f};
        acc = __builtin_amdgcn_mfma_f32_16x16x32_bf16(wf[s][mtv][0], b0.s8,
                                                      acc, 0, 0, 0);
        acc = __builtin_amdgcn_mfma_f32_16x16x32_bf16(wf[s][mtv][1], b1.s8,
                                                      acc, 0, 0, 0);
        va[m] = acc;
      }
#pragma unroll
      for (int r = 0; r < 4; ++r) {
        float mux = va[0][r], muy = va[1][r], m2 = va[2][r], mxy = va[3][r];
        float mux2 = mux * mux, muy2 = muy * muy, muxy = mux * muy;
        float cs = (2.f * (mxy - muxy) + kC2) * frcp((m2 - mux2 - muy2) + kC2);
        Pcs[r] *= cs;
        if (s == 1) {
          lumP[r] = ((2.f * muxy + kC1) * frcp(mux2 + muy2 + kC1)) * Pcs[r];
          l1v[r] = va[4][r] * corr;
        }
      }
    }
  }

  // loss_mix = alpha*(1 - lum*PIcs) + (1-alpha)*gaussian_l1 ; out = 20*mean
  float lsum = 0.f;
#pragma unroll
  for (int r = 0; r < 4; ++r)
    lsum += kAlpha * (1.f - lumP[r]) + (1.f - kAlpha) * l1v[r];
#pragma unroll
  for (int off = 32; off > 0; off >>= 1) lsum += __shfl_down(lsum, off, 64);
  if ((tid & 63) == 0) sm.red[tid >> 6] = lsum;
  __syncthreads();  // B6
  if (tid == 0) {
    float t = sm.red[0] + sm.red[1] + sm.red[2] + sm.red[3];
    atomicAdd(out, t * (20.f / (16.f * 512.f * 512.f)));
  }
}

}  // namespace

extern "C" void kernel_launch(void* const* d_in, const int* in_sizes, int n_in,
                              void* d_out, int out_size, void* d_ws,
                              size_t ws_size, hipStream_t stream) {
  (void)in_sizes;
  (void)n_in;
  (void)d_ws;
  (void)ws_size;
  (void)out_size;
  const float* x = (const float*)d_in[0];
  const float* y = (const float*)d_in[1];
  const float* gm = (const float*)d_in[2];
  float* out = (float*)d_out;
  hipMemsetAsync(out, 0, sizeof(float), stream);
  dim3 grid(16, 16, 16);
  msssim_l1_kernel<<<grid, dim3(256), 0, stream>>>(x, y, gm, out);
}

// Round 12
// 159.143 us; speedup vs baseline: 1.8875x; 1.8875x over previous
//
#include <hip/hip_runtime.h>
#include <hip/hip_bf16.h>

namespace {

constexpr float kAlpha = 0.025f;
constexpr float kC1 = 1.0e-4f;  // (0.01*1)^2
constexpr float kC2 = 9.0e-4f;  // (0.03*1)^2

constexpr int MPS = 68;  // mp row stride (shorts): 136 B, b64-aligned rows
constexpr int HTS = 68;  // hbT col stride (shorts): 136 B, b64-aligned

typedef __attribute__((ext_vector_type(8))) short short8;
typedef __attribute__((ext_vector_type(4))) float f32x4;

// LDS: union(mp 17.4 KB, hbT 52.2 KB) + red = 52.3 KB -> 3 blocks/CU
// group1 planes: sigma s in {0,1,2}, map m -> plane s*4+m  (12 planes)
// group2 planes: sigma 3 map m -> plane m; sigma 4 map m -> plane 4+m; d -> 8
struct __align__(16) Smem {
  union {
    short mp[2][64 * MPS];    // bf16 pixel maps: x, y (staging only)
    short hbT[12][32 * HTS];  // bf16 H results, transposed [out_col][row]
  };
  float red[4];
};

union Frag {
  int i[4];
  short8 s8;
};

__device__ __forceinline__ unsigned f2bf(float f) {  // RNE fp32 -> bf16 bits
  unsigned u = __float_as_uint(f);
  return (u + 0x7FFFu + ((u >> 16) & 1u)) >> 16;
}
__device__ __forceinline__ unsigned pk(float a, float b) {  // v_cvt_pk_bf16
  union {
    __hip_bfloat162 h;
    unsigned u;
  } c;
  c.h = __float22bfloat162_rn(make_float2(a, b));
  return c.u;
}
__device__ __forceinline__ float bfl(unsigned u) {
  return __uint_as_float(u << 16);
}
__device__ __forceinline__ float bfh(unsigned u) {
  return __uint_as_float(u & 0xFFFF0000u);
}
__device__ __forceinline__ float frcp(float x) {  // v_rcp_f32, ~1 ulp
  return __builtin_amdgcn_rcpf(x);
}

// W fragment via lane shuffles: element (p,h) = g[k - n],
// k = kt*32 + quad*8 + 2p+h, n = nt*16 + l16; lanes >= 33 hold 0 and the
// &63 wrap maps every out-of-band index onto a zero lane. Symmetric for
// A-operand (V pass) and B-operand (H pass) layouts.
__device__ __forceinline__ short8 wbuild(unsigned tb, int lane, int nt,
                                         int kt) {
  const int b0 = (lane >> 4) * 8 - (lane & 15) + 32 * kt - 16 * nt;
  Frag u;
#pragma unroll
  for (int p = 0; p < 4; ++p) {
    unsigned lo = (unsigned)__shfl((int)tb, (b0 + 2 * p) & 63, 64);
    unsigned hi = (unsigned)__shfl((int)tb, (b0 + 2 * p + 1) & 63, 64);
    u.i[p] = (int)(lo | (hi << 16));
  }
  return u.s8;
}

__device__ __forceinline__ void load_xy(const Smem& sm, int row, int quad,
                                        Frag fx[2], Frag fy[2]) {
  const short* px = &sm.mp[0][row * MPS + quad * 8];
  const short* py = &sm.mp[1][row * MPS + quad * 8];
  *(int2*)&fx[0].i[0] = *(const int2*)(px);
  *(int2*)&fx[0].i[2] = *(const int2*)(px + 4);
  *(int2*)&fx[1].i[0] = *(const int2*)(px + 32);
  *(int2*)&fx[1].i[2] = *(const int2*)(px + 36);
  *(int2*)&fy[0].i[0] = *(const int2*)(py);
  *(int2*)&fy[0].i[2] = *(const int2*)(py + 4);
  *(int2*)&fy[1].i[0] = *(const int2*)(py + 32);
  *(int2*)&fy[1].i[2] = *(const int2*)(py + 36);
}

__global__ __launch_bounds__(256, 2) void msssim_l1_kernel(
    const float* __restrict__ x, const float* __restrict__ y,
    const float* __restrict__ gm, float* __restrict__ out) {
  __shared__ Smem sm;
  const int tid = threadIdx.x;
  const int lane = tid & 63;
  const int w = tid >> 6;
  const int quad = lane >> 4;
  const int l16 = lane & 15;

  // per-lane taps (lane j<33 holds m[16][j]); per-sigma bf16 tap bits
  float traw[5];
#pragma unroll
  for (int s = 0; s < 5; ++s)
    traw[s] = (lane < 33) ? gm[s * 1089 + 16 * 33 + lane] : 0.f;
  unsigned tbs[5];
#pragma unroll
  for (int s = 0; s < 5; ++s)
    tbs[s] = f2bf(traw[s] * rsqrtf(__shfl(traw[s], 16, 64)));
  float corr;  // fp32/bf16 tap-sum compensation for the l1 conv (sigma 4)
  {
    float g = traw[4] * rsqrtf(__shfl(traw[4], 16, 64));
    float se = g, st = bfl(f2bf(g));
#pragma unroll
    for (int off = 32; off > 0; off >>= 1) {
      se += __shfl_xor(se, off, 64);
      st += __shfl_xor(st, off, 64);
    }
    float r1 = se / st;
    corr = r1 * r1;
  }

  // 64x64 halo patch, zero-padded; bf16 x/y maps in LDS (mp region)
  const float* xb = x + blockIdx.z * (512 * 512);
  const float* yb = y + blockIdx.z * (512 * 512);
  const int rb = blockIdx.y * 32 - 16;
  const int cb = blockIdx.x * 32 - 16;
  for (int f = tid; f < 1024; f += 256) {
    int pr = f >> 4;
    int pc = (f & 15) << 2;
    int gr = rb + pr, gc = cb + pc;
    float4 vx = make_float4(0.f, 0.f, 0.f, 0.f);
    float4 vy = vx;
    if (gr >= 0 && gr < 512 && gc >= 0 && gc < 512) {
      vx = *(const float4*)(xb + gr * 512 + gc);
      vy = *(const float4*)(yb + gr * 512 + gc);
    }
    const int base = pr * MPS + pc;
    *(int2*)(&sm.mp[0][base]) =
        make_int2((int)pk(vx.x, vx.y), (int)pk(vx.z, vx.w));
    *(int2*)(&sm.mp[1][base]) =
        make_int2((int)pk(vy.x, vy.y), (int)pk(vy.z, vy.w));
  }
  __syncthreads();  // B1: patch ready

  // persistent A-fragments for THIS wave's map (m = w), all 4 row tiles;
  // every wave also builds |x-y| fragments for ITS OWN mtile (mt == w)
  Frag A[4][2];
  Frag dA[2];
#pragma unroll
  for (int mt = 0; mt < 4; ++mt) {
    Frag fx[2], fy[2];
    load_xy(sm, mt * 16 + l16, quad, fx, fy);
    if (mt == w) {  // own-mtile |x-y| fragments (plane 8, balanced)
#pragma unroll
      for (int h = 0; h < 2; ++h)
#pragma unroll
        for (int i = 0; i < 4; ++i) {
          unsigned ux = (unsigned)fx[h].i[i], uy = (unsigned)fy[h].i[i];
          dA[h].i[i] =
              (int)pk(fabsf(bfl(ux) - bfl(uy)), fabsf(bfh(ux) - bfh(uy)));
        }
    }
    if (w == 0) {
      A[mt][0] = fx[0];
      A[mt][1] = fx[1];
    } else if (w == 1) {
      A[mt][0] = fy[0];
      A[mt][1] = fy[1];
    } else {
#pragma unroll
      for (int h = 0; h < 2; ++h)
#pragma unroll
        for (int i = 0; i < 4; ++i) {
          unsigned ux = (unsigned)fx[h].i[i], uy = (unsigned)fy[h].i[i];
          float xl = bfl(ux), xh = bfh(ux), yl = bfl(uy), yh = bfh(uy);
          A[mt][h].i[i] = (w == 2) ? (int)pk(fmaf(xl, xl, yl * yl),
                                            fmaf(xh, xh, yh * yh))
                                   : (int)pk(xl * yl, xh * yh);
        }
    }
  }
  __syncthreads();  // B2: all mp reads done -> hbT may overwrite the union

  const int mtv = w >> 1, ntv = w & 1;
  f32x4 Pcs = {1.f, 1.f, 1.f, 1.f};
  f32x4 lumP = {0.f, 0.f, 0.f, 0.f};
  f32x4 l1v = {0.f, 0.f, 0.f, 0.f};

  // ================= group 1: sigmas 0..2 =================
#pragma unroll
  for (int s = 0; s < 3; ++s) {  // H: wave w = map w, plane s*4+w
    short8 wf[2][2];
#pragma unroll
    for (int nt = 0; nt < 2; ++nt)
#pragma unroll
      for (int kt = 0; kt < 2; ++kt) wf[nt][kt] = wbuild(tbs[s], lane, nt, kt);
#pragma unroll
    for (int mt = 0; mt < 4; ++mt)
#pragma unroll
      for (int nt = 0; nt < 2; ++nt) {
        f32x4 acc = {0.f, 0.f, 0.f, 0.f};
        acc = __builtin_amdgcn_mfma_f32_16x16x32_bf16(A[mt][0].s8, wf[nt][0],
                                                      acc, 0, 0, 0);
        acc = __builtin_amdgcn_mfma_f32_16x16x32_bf16(A[mt][1].s8, wf[nt][1],
                                                      acc, 0, 0, 0);
        *(int2*)(&sm.hbT[s * 4 + w][(nt * 16 + l16) * HTS + mt * 16 +
                                    quad * 4]) =
            make_int2((int)pk(acc[0], acc[1]), (int)pk(acc[2], acc[3]));
      }
  }
  __syncthreads();  // B3: group-1 hbT ready

#pragma unroll
  for (int s = 0; s < 3; ++s) {  // V + combine: wave = output quadrant
    short8 wa0 = wbuild(tbs[s], lane, mtv, 0);
    short8 wa1 = wbuild(tbs[s], lane, mtv, 1);
    f32x4 va[4];
#pragma unroll
    for (int m = 0; m < 4; ++m) {
      const short* bp = &sm.hbT[s * 4 + m][(ntv * 16 + l16) * HTS + quad * 8];
      Frag b0, b1;
      *(int2*)&b0.i[0] = *(const int2*)(bp);
      *(int2*)&b0.i[2] = *(const int2*)(bp + 4);
      *(int2*)&b1.i[0] = *(const int2*)(bp + 32);
      *(int2*)&b1.i[2] = *(const int2*)(bp + 36);
      f32x4 acc = {0.f, 0.f, 0.f, 0.f};
      acc = __builtin_amdgcn_mfma_f32_16x16x32_bf16(wa0, b0.s8, acc, 0, 0, 0);
      acc = __builtin_amdgcn_mfma_f32_16x16x32_bf16(wa1, b1.s8, acc, 0, 0, 0);
      va[m] = acc;
    }
#pragma unroll
    for (int r = 0; r < 4; ++r) {
      float mux = va[0][r], muy = va[1][r], m2 = va[2][r], mxy = va[3][r];
      float cs = (2.f * (mxy - mux * muy) + kC2) *
                 frcp((m2 - mux * mux - muy * muy) + kC2);
      Pcs[r] *= cs;
    }
  }
  __syncthreads();  // B4: group-1 V reads done, hbT reusable

  // ================= group 2: sigmas 3,4 =================
#pragma unroll
  for (int s = 3; s < 5; ++s) {
    const int pb = (s == 3) ? 0 : 4;
    short8 wf[2][2];
#pragma unroll
    for (int nt = 0; nt < 2; ++nt)
#pragma unroll
      for (int kt = 0; kt < 2; ++kt) wf[nt][kt] = wbuild(tbs[s], lane, nt, kt);
#pragma unroll
    for (int mt = 0; mt < 4; ++mt)
#pragma unroll
      for (int nt = 0; nt < 2; ++nt) {
        f32x4 acc = {0.f, 0.f, 0.f, 0.f};
        acc = __builtin_amdgcn_mfma_f32_16x16x32_bf16(A[mt][0].s8, wf[nt][0],
                                                      acc, 0, 0, 0);
        acc = __builtin_amdgcn_mfma_f32_16x16x32_bf16(A[mt][1].s8, wf[nt][1],
                                                      acc, 0, 0, 0);
        *(int2*)(&sm.hbT[pb + w][(nt * 16 + l16) * HTS + mt * 16 + quad * 4]) =
            make_int2((int)pk(acc[0], acc[1]), (int)pk(acc[2], acc[3]));
      }
    if (s == 4) {  // plane 8 (sigma-4 |x-y|): each wave does ITS mtile (= w)
#pragma unroll
      for (int nt = 0; nt < 2; ++nt) {
        f32x4 acc = {0.f, 0.f, 0.f, 0.f};
        acc = __builtin_amdgcn_mfma_f32_16x16x32_bf16(dA[0].s8, wf[nt][0], acc,
                                                      0, 0, 0);
        acc = __builtin_amdgcn_mfma_f32_16x16x32_bf16(dA[1].s8, wf[nt][1], acc,
                                                      0, 0, 0);
        *(int2*)(&sm.hbT[8][(nt * 16 + l16) * HTS + w * 16 + quad * 4]) =
            make_int2((int)pk(acc[0], acc[1]), (int)pk(acc[2], acc[3]));
      }
    }
  }
  __syncthreads();  // B5: group-2 hbT ready

#pragma unroll
  for (int s = 3; s < 5; ++s) {
    const int pb = (s == 3) ? 0 : 4;
    const int nm = (s == 3) ? 4 : 5;
    short8 wa0 = wbuild(tbs[s], lane, mtv, 0);
    short8 wa1 = wbuild(tbs[s], lane, mtv, 1);
    f32x4 va[5];
#pragma unroll
    for (int m = 0; m < 5; ++m) {
      if (m >= nm) continue;
      const short* bp = &sm.hbT[pb + m][(ntv * 16 + l16) * HTS + quad * 8];
      Frag b0, b1;
      *(int2*)&b0.i[0] = *(const int2*)(bp);
      *(int2*)&b0.i[2] = *(const int2*)(bp + 4);
      *(int2*)&b1.i[0] = *(const int2*)(bp + 32);
      *(int2*)&b1.i[2] = *(const int2*)(bp + 36);
      f32x4 acc = {0.f, 0.f, 0.f, 0.f};
      acc = __builtin_amdgcn_mfma_f32_16x16x32_bf16(wa0, b0.s8, acc, 0, 0, 0);
      acc = __builtin_amdgcn_mfma_f32_16x16x32_bf16(wa1, b1.s8, acc, 0, 0, 0);
      va[m] = acc;
    }
#pragma unroll
    for (int r = 0; r < 4; ++r) {
      float mux = va[0][r], muy = va[1][r], m2 = va[2][r], mxy = va[3][r];
      float mux2 = mux * mux, muy2 = muy * muy, muxy = mux * muy;
      float cs = (2.f * (mxy - muxy) + kC2) * frcp((m2 - mux2 - muy2) + kC2);
      Pcs[r] *= cs;
      if (s == 4) {
        lumP[r] = ((2.f * muxy + kC1) * frcp(mux2 + muy2 + kC1)) * Pcs[r];
        l1v[r] = va[4][r] * corr;
      }
    }
  }

  // loss_mix = alpha*(1 - lum*PIcs) + (1-alpha)*gaussian_l1 ; out = 20*mean
  float lsum = 0.f;
#pragma unroll
  for (int r = 0; r < 4; ++r)
    lsum += kAlpha * (1.f - lumP[r]) + (1.f - kAlpha) * l1v[r];
#pragma unroll
  for (int off = 32; off > 0; off >>= 1) lsum += __shfl_down(lsum, off, 64);
  if ((tid & 63) == 0) sm.red[tid >> 6] = lsum;
  __syncthreads();  // B6
  if (tid == 0) {
    float t = sm.red[0] + sm.red[1] + sm.red[2] + sm.red[3];
    atomicAdd(out, t * (20.f / (16.f * 512.f * 512.f)));
  }
}

}  // namespace

extern "C" void kernel_launch(void* const* d_in, const int* in_sizes, int n_in,
                              void* d_out, int out_size, void* d_ws,
                              size_t ws_size, hipStream_t stream) {
  (void)in_sizes;
  (void)n_in;
  (void)d_ws;
  (void)ws_size;
  (void)out_size;
  const float* x = (const float*)d_in[0];
  const float* y = (const float*)d_in[1];
  const float* gm = (const float*)d_in[2];
  float* out = (float*)d_out;
  hipMemsetAsync(out, 0, sizeof(float), stream);
  dim3 grid(16, 16, 16);
  msssim_l1_kernel<<<grid, dim3(256), 0, stream>>>(x, y, gm, out);
}

// Round 13
// 154.480 us; speedup vs baseline: 1.9445x; 1.0302x over previous
//
#include <hip/hip_runtime.h>
#include <hip/hip_bf16.h>

namespace {

constexpr float kAlpha = 0.025f;
constexpr float kC1 = 1.0e-4f;  // (0.01*1)^2
constexpr float kC2 = 9.0e-4f;  // (0.03*1)^2

constexpr int MPS = 68;  // mp row stride (shorts): 136 B, b64-aligned rows
constexpr int HTS = 68;  // hbT col stride (shorts): 136 B, b64-aligned

typedef __attribute__((ext_vector_type(8))) short short8;
typedef __attribute__((ext_vector_type(4))) float f32x4;

// LDS: union(mp 17.4 KB, hbT 52.2 KB) + red + gtab 1.9 KB = 54160 B
// -> rounds to 54272 (512 B granule) -> 3 blocks/CU (3*54272 <= 160 KB)
// group1 planes: sigma s in {0,1,2}, map m -> plane s*4+m  (12 planes)
// group2 planes: sigma 3 map m -> plane m; sigma 4 map m -> plane 4+m; d -> 8
struct __align__(16) Smem {
  union {
    short mp[2][64 * MPS];    // bf16 pixel maps: x, y (staging only)
    short hbT[12][32 * HTS];  // bf16 H results, transposed [out_col][row]
  };
  float red[4];
  // tap tables: entry e[t] = bf16(g[t-31]) for t-31 in [0,32], else 0.
  // gtab[0][s][i] = (e[2i], e[2i+1])   (even-start pairs)
  // gtab[1][s][i] = (e[2i+1], e[2i+2]) (odd-start pairs)
  int gtab[2][5][48];
};

union Frag {
  int i[4];
  short8 s8;
};

__device__ __forceinline__ unsigned f2bf(float f) {  // RNE fp32 -> bf16 bits
  unsigned u = __float_as_uint(f);
  return (u + 0x7FFFu + ((u >> 16) & 1u)) >> 16;
}
__device__ __forceinline__ unsigned pk(float a, float b) {  // v_cvt_pk_bf16
  union {
    __hip_bfloat162 h;
    unsigned u;
  } c;
  c.h = __float22bfloat162_rn(make_float2(a, b));
  return c.u;
}
__device__ __forceinline__ float bfl(unsigned u) {
  return __uint_as_float(u << 16);
}
__device__ __forceinline__ float bfh(unsigned u) {
  return __uint_as_float(u & 0xFFFF0000u);
}
__device__ __forceinline__ float frcp(float x) {  // v_rcp_f32, ~1 ulp
  return __builtin_amdgcn_rcpf(x);
}

// W fragment from the parity table: element j of (nt,kt) = g[k-n],
// k = kt*32 + quad*8 + j, n = nt*16 + l16. Start index t0 = idx0+31 has
// lane-only parity, so per-lane table base (tb) is fixed; fragment = 4
// consecutive dwords at tb[16kt - 8nt + 8 + j] (compiler -> 2x ds_read2_b32).
// Symmetric for A-operand (V pass, nt=mtile) and B-operand (H pass).
__device__ __forceinline__ short8 wbuild2(const int* tb, int nt, int kt) {
  Frag u;
#pragma unroll
  for (int j = 0; j < 4; ++j) u.i[j] = tb[16 * kt - 8 * nt + 8 + j];
  return u.s8;
}

__device__ __forceinline__ void load_xy(const Smem& sm, int row, int quad,
                                        Frag fx[2], Frag fy[2]) {
  const short* px = &sm.mp[0][row * MPS + quad * 8];
  const short* py = &sm.mp[1][row * MPS + quad * 8];
  *(int2*)&fx[0].i[0] = *(const int2*)(px);
  *(int2*)&fx[0].i[2] = *(const int2*)(px + 4);
  *(int2*)&fx[1].i[0] = *(const int2*)(px + 32);
  *(int2*)&fx[1].i[2] = *(const int2*)(px + 36);
  *(int2*)&fy[0].i[0] = *(const int2*)(py);
  *(int2*)&fy[0].i[2] = *(const int2*)(py + 4);
  *(int2*)&fy[1].i[0] = *(const int2*)(py + 32);
  *(int2*)&fy[1].i[2] = *(const int2*)(py + 36);
}

__global__ __launch_bounds__(256, 2) void msssim_l1_kernel(
    const float* __restrict__ x, const float* __restrict__ y,
    const float* __restrict__ gm, float* __restrict__ out) {
  __shared__ Smem sm;
  const int tid = threadIdx.x;
  const int lane = tid & 63;
  const int w = tid >> 6;
  const int quad = lane >> 4;
  const int l16 = lane & 15;

  // corr: fp32/bf16 tap-sum compensation for the l1 conv (sigma 4)
  float corr;
  {
    float traw4 = (lane < 33) ? gm[4 * 1089 + 528 + lane] : 0.f;
    float g = traw4 * rsqrtf(__shfl(traw4, 16, 64));
    float se = g, st = bfl(f2bf(g));
#pragma unroll
    for (int off = 32; off > 0; off >>= 1) {
      se += __shfl_xor(se, off, 64);
      st += __shfl_xor(st, off, 64);
    }
    float r1 = se / st;
    corr = r1 * r1;
  }

  // build dual-parity tap tables (480 dwords; gm is L2-hot, 21.8 KB)
  {
    int* gt = &sm.gtab[0][0][0];
    for (int q = tid; q < 480; q += 256) {
      int par = q >= 240;
      int rem = par ? q - 240 : q;
      int s = rem / 48;
      int i = rem - s * 48;
      int t0 = 2 * i + par;
      const float* grow = gm + s * 1089 + 528;
      float rsc = rsqrtf(grow[16]);
      int g0 = t0 - 31, g1 = t0 - 30;
      unsigned lo = (g0 >= 0 && g0 <= 32) ? f2bf(grow[g0] * rsc) : 0u;
      unsigned hi = (g1 >= 0 && g1 <= 32) ? f2bf(grow[g1] * rsc) : 0u;
      gt[q] = (int)(lo | (hi << 16));
    }
  }

  // per-lane table base: parity of t0 = (l16+1)&1; D = (quad*8 - l16 + 31)>>1
  // bias -8 so all wbuild2 immediate offsets are non-negative
  const int D = (quad * 8 - l16 + 31) >> 1;
  const int* gD = &sm.gtab[(l16 & 1) ? 0 : 1][0][0] + D - 8;

  // 64x64 halo patch, zero-padded; bf16 x/y maps in LDS (mp region)
  const float* xb = x + blockIdx.z * (512 * 512);
  const float* yb = y + blockIdx.z * (512 * 512);
  const int rb = blockIdx.y * 32 - 16;
  const int cb = blockIdx.x * 32 - 16;
  for (int f = tid; f < 1024; f += 256) {
    int pr = f >> 4;
    int pc = (f & 15) << 2;
    int gr = rb + pr, gc = cb + pc;
    float4 vx = make_float4(0.f, 0.f, 0.f, 0.f);
    float4 vy = vx;
    if (gr >= 0 && gr < 512 && gc >= 0 && gc < 512) {
      vx = *(const float4*)(xb + gr * 512 + gc);
      vy = *(const float4*)(yb + gr * 512 + gc);
    }
    const int base = pr * MPS + pc;
    *(int2*)(&sm.mp[0][base]) =
        make_int2((int)pk(vx.x, vx.y), (int)pk(vx.z, vx.w));
    *(int2*)(&sm.mp[1][base]) =
        make_int2((int)pk(vy.x, vy.y), (int)pk(vy.z, vy.w));
  }
  __syncthreads();  // B1: patch + tables ready

  // persistent A-fragments for THIS wave's map (m = w), all 4 row tiles;
  // every wave also builds |x-y| fragments for ITS OWN mtile (mt == w)
  Frag A[4][2];
  Frag dA[2];
#pragma unroll
  for (int mt = 0; mt < 4; ++mt) {
    Frag fx[2], fy[2];
    load_xy(sm, mt * 16 + l16, quad, fx, fy);
    if (mt == w) {  // own-mtile |x-y| fragments (plane 8, balanced)
#pragma unroll
      for (int h = 0; h < 2; ++h)
#pragma unroll
        for (int i = 0; i < 4; ++i) {
          unsigned ux = (unsigned)fx[h].i[i], uy = (unsigned)fy[h].i[i];
          dA[h].i[i] =
              (int)pk(fabsf(bfl(ux) - bfl(uy)), fabsf(bfh(ux) - bfh(uy)));
        }
    }
    if (w == 0) {
      A[mt][0] = fx[0];
      A[mt][1] = fx[1];
    } else if (w == 1) {
      A[mt][0] = fy[0];
      A[mt][1] = fy[1];
    } else {
#pragma unroll
      for (int h = 0; h < 2; ++h)
#pragma unroll
        for (int i = 0; i < 4; ++i) {
          unsigned ux = (unsigned)fx[h].i[i], uy = (unsigned)fy[h].i[i];
          float xl = bfl(ux), xh = bfh(ux), yl = bfl(uy), yh = bfh(uy);
          A[mt][h].i[i] = (w == 2) ? (int)pk(fmaf(xl, xl, yl * yl),
                                            fmaf(xh, xh, yh * yh))
                                   : (int)pk(xl * yl, xh * yh);
        }
    }
  }
  __syncthreads();  // B2: all mp reads done -> hbT may overwrite the union

  const int mtv = w >> 1, ntv = w & 1;
  f32x4 Pcs = {1.f, 1.f, 1.f, 1.f};
  f32x4 lumP = {0.f, 0.f, 0.f, 0.f};
  f32x4 l1v = {0.f, 0.f, 0.f, 0.f};

  // ================= group 1: sigmas 0..2 =================
#pragma unroll
  for (int s = 0; s < 3; ++s) {  // H: wave w = map w, plane s*4+w
    const int* tb = gD + s * 48;
    short8 wf[2][2];
#pragma unroll
    for (int nt = 0; nt < 2; ++nt)
#pragma unroll
      for (int kt = 0; kt < 2; ++kt) wf[nt][kt] = wbuild2(tb, nt, kt);
#pragma unroll
    for (int mt = 0; mt < 4; ++mt)
#pragma unroll
      for (int nt = 0; nt < 2; ++nt) {
        f32x4 acc = {0.f, 0.f, 0.f, 0.f};
        acc = __builtin_amdgcn_mfma_f32_16x16x32_bf16(A[mt][0].s8, wf[nt][0],
                                                      acc, 0, 0, 0);
        acc = __builtin_amdgcn_mfma_f32_16x16x32_bf16(A[mt][1].s8, wf[nt][1],
                                                      acc, 0, 0, 0);
        *(int2*)(&sm.hbT[s * 4 + w][(nt * 16 + l16) * HTS + mt * 16 +
                                    quad * 4]) =
            make_int2((int)pk(acc[0], acc[1]), (int)pk(acc[2], acc[3]));
      }
  }
  __syncthreads();  // B3: group-1 hbT ready

#pragma unroll
  for (int s = 0; s < 3; ++s) {  // V + combine: wave = output quadrant
    const int* tb = gD + s * 48;
    short8 wa0 = wbuild2(tb, mtv, 0);
    short8 wa1 = wbuild2(tb, mtv, 1);
    f32x4 va[4];
#pragma unroll
    for (int m = 0; m < 4; ++m) {
      const short* bp = &sm.hbT[s * 4 + m][(ntv * 16 + l16) * HTS + quad * 8];
      Frag b0, b1;
      *(int2*)&b0.i[0] = *(const int2*)(bp);
      *(int2*)&b0.i[2] = *(const int2*)(bp + 4);
      *(int2*)&b1.i[0] = *(const int2*)(bp + 32);
      *(int2*)&b1.i[2] = *(const int2*)(bp + 36);
      f32x4 acc = {0.f, 0.f, 0.f, 0.f};
      acc = __builtin_amdgcn_mfma_f32_16x16x32_bf16(wa0, b0.s8, acc, 0, 0, 0);
      acc = __builtin_amdgcn_mfma_f32_16x16x32_bf16(wa1, b1.s8, acc, 0, 0, 0);
      va[m] = acc;
    }
#pragma unroll
    for (int r = 0; r < 4; ++r) {
      float mux = va[0][r], muy = va[1][r], m2 = va[2][r], mxy = va[3][r];
      float cs = (2.f * (mxy - mux * muy) + kC2) *
                 frcp((m2 - mux * mux - muy * muy) + kC2);
      Pcs[r] *= cs;
    }
  }
  __syncthreads();  // B4: group-1 V reads done, hbT reusable

  // ================= group 2: sigmas 3,4 =================
#pragma unroll
  for (int s = 3; s < 5; ++s) {
    const int pb = (s == 3) ? 0 : 4;
    const int* tb = gD + s * 48;
    short8 wf[2][2];
#pragma unroll
    for (int nt = 0; nt < 2; ++nt)
#pragma unroll
      for (int kt = 0; kt < 2; ++kt) wf[nt][kt] = wbuild2(tb, nt, kt);
#pragma unroll
    for (int mt = 0; mt < 4; ++mt)
#pragma unroll
      for (int nt = 0; nt < 2; ++nt) {
        f32x4 acc = {0.f, 0.f, 0.f, 0.f};
        acc = __builtin_amdgcn_mfma_f32_16x16x32_bf16(A[mt][0].s8, wf[nt][0],
                                                      acc, 0, 0, 0);
        acc = __builtin_amdgcn_mfma_f32_16x16x32_bf16(A[mt][1].s8, wf[nt][1],
                                                      acc, 0, 0, 0);
        *(int2*)(&sm.hbT[pb + w][(nt * 16 + l16) * HTS + mt * 16 + quad * 4]) =
            make_int2((int)pk(acc[0], acc[1]), (int)pk(acc[2], acc[3]));
      }
    if (s == 4) {  // plane 8 (sigma-4 |x-y|): each wave does ITS mtile (= w)
#pragma unroll
      for (int nt = 0; nt < 2; ++nt) {
        f32x4 acc = {0.f, 0.f, 0.f, 0.f};
        acc = __builtin_amdgcn_mfma_f32_16x16x32_bf16(dA[0].s8, wf[nt][0], acc,
                                                      0, 0, 0);
        acc = __builtin_amdgcn_mfma_f32_16x16x32_bf16(dA[1].s8, wf[nt][1], acc,
                                                      0, 0, 0);
        *(int2*)(&sm.hbT[8][(nt * 16 + l16) * HTS + w * 16 + quad * 4]) =
            make_int2((int)pk(acc[0], acc[1]), (int)pk(acc[2], acc[3]));
      }
    }
  }
  __syncthreads();  // B5: group-2 hbT ready

#pragma unroll
  for (int s = 3; s < 5; ++s) {
    const int pb = (s == 3) ? 0 : 4;
    const int nm = (s == 3) ? 4 : 5;
    const int* tb = gD + s * 48;
    short8 wa0 = wbuild2(tb, mtv, 0);
    short8 wa1 = wbuild2(tb, mtv, 1);
    f32x4 va[5];
#pragma unroll
    for (int m = 0; m < 5; ++m) {
      if (m >= nm) continue;
      const short* bp = &sm.hbT[pb + m][(ntv * 16 + l16) * HTS + quad * 8];
      Frag b0, b1;
      *(int2*)&b0.i[0] = *(const int2*)(bp);
      *(int2*)&b0.i[2] = *(const int2*)(bp + 4);
      *(int2*)&b1.i[0] = *(const int2*)(bp + 32);
      *(int2*)&b1.i[2] = *(const int2*)(bp + 36);
      f32x4 acc = {0.f, 0.f, 0.f, 0.f};
      acc = __builtin_amdgcn_mfma_f32_16x16x32_bf16(wa0, b0.s8, acc, 0, 0, 0);
      acc = __builtin_amdgcn_mfma_f32_16x16x32_bf16(wa1, b1.s8, acc, 0, 0, 0);
      va[m] = acc;
    }
#pragma unroll
    for (int r = 0; r < 4; ++r) {
      float mux = va[0][r], muy = va[1][r], m2 = va[2][r], mxy = va[3][r];
      float mux2 = mux * mux, muy2 = muy * muy, muxy = mux * muy;
      float cs = (2.f * (mxy - muxy) + kC2) * frcp((m2 - mux2 - muy2) + kC2);
      Pcs[r] *= cs;
      if (s == 4) {
        lumP[r] = ((2.f * muxy + kC1) * frcp(mux2 + muy2 + kC1)) * Pcs[r];
        l1v[r] = va[4][r] * corr;
      }
    }
  }

  // loss_mix = alpha*(1 - lum*PIcs) + (1-alpha)*gaussian_l1 ; out = 20*mean
  float lsum = 0.f;
#pragma unroll
  for (int r = 0; r < 4; ++r)
    lsum += kAlpha * (1.f - lumP[r]) + (1.f - kAlpha) * l1v[r];
#pragma unroll
  for (int off = 32; off > 0; off >>= 1) lsum += __shfl_down(lsum, off, 64);
  if ((tid & 63) == 0) sm.red[tid >> 6] = lsum;
  __syncthreads();  // B6
  if (tid == 0) {
    float t = sm.red[0] + sm.red[1] + sm.red[2] + sm.red[3];
    atomicAdd(out, t * (20.f / (16.f * 512.f * 512.f)));
  }
}

}  // namespace

extern "C" void kernel_launch(void* const* d_in, const int* in_sizes, int n_in,
                              void* d_out, int out_size, void* d_ws,
                              size_t ws_size, hipStream_t stream) {
  (void)in_sizes;
  (void)n_in;
  (void)d_ws;
  (void)ws_size;
  (void)out_size;
  const float* x = (const float*)d_in[0];
  const float* y = (const float*)d_in[1];
  const float* gm = (const float*)d_in[2];
  float* out = (float*)d_out;
  hipMemsetAsync(out, 0, sizeof(float), stream);
  dim3 grid(16, 16, 16);
  msssim_l1_kernel<<<grid, dim3(256), 0, stream>>>(x, y, gm, out);
}

// Round 14
// 145.590 us; speedup vs baseline: 2.0632x; 1.0611x over previous
//
#include <hip/hip_runtime.h>
#include <hip/hip_bf16.h>

namespace {

constexpr float kAlpha = 0.025f;
constexpr float kC1 = 1.0e-4f;  // (0.01*1)^2
constexpr float kC2 = 9.0e-4f;  // (0.03*1)^2

constexpr int MPS = 68;  // mp row stride (shorts): 136 B, b64-aligned rows
constexpr int HTS = 68;  // hbT col stride (shorts): 136 B, b64-aligned

typedef __attribute__((ext_vector_type(8))) short short8;
typedef __attribute__((ext_vector_type(4))) float f32x4;

// LDS: union(mp 17408 B, hbT 8*4352=34816 B) + red + gtab 1920 B = 36752 B
// -> ~36864 alloc -> 4 blocks/CU (4*36864 = 147456 <= 160 KB even w/ reserve)
// Sigma groups: {0,1} planes s*4+m (8); {2,3} planes (s-2)*4+m (8);
// {4} planes m (4 maps) + plane 4 = |x-y|.
struct __align__(16) Smem {
  union {
    short mp[2][64 * MPS];   // bf16 pixel maps: x, y (staging only)
    short hbT[8][32 * HTS];  // bf16 H results, transposed [out_col][row]
  };
  float red[4];
  // tap tables: entry e[t] = bf16(g[t-31]) for t-31 in [0,32], else 0.
  // gtab[0][s][i] = (e[2i], e[2i+1]); gtab[1][s][i] = (e[2i+1], e[2i+2])
  int gtab[2][5][48];
};

union Frag {
  int i[4];
  short8 s8;
};

__device__ __forceinline__ unsigned f2bf(float f) {  // RNE fp32 -> bf16 bits
  unsigned u = __float_as_uint(f);
  return (u + 0x7FFFu + ((u >> 16) & 1u)) >> 16;
}
__device__ __forceinline__ unsigned pk(float a, float b) {  // v_cvt_pk_bf16
  union {
    __hip_bfloat162 h;
    unsigned u;
  } c;
  c.h = __float22bfloat162_rn(make_float2(a, b));
  return c.u;
}
__device__ __forceinline__ float bfl(unsigned u) {
  return __uint_as_float(u << 16);
}
__device__ __forceinline__ float bfh(unsigned u) {
  return __uint_as_float(u & 0xFFFF0000u);
}
__device__ __forceinline__ float frcp(float x) {  // v_rcp_f32, ~1 ulp
  return __builtin_amdgcn_rcpf(x);
}

// W fragment from the parity table: element j of (nt,kt) = g[k-n],
// k = kt*32 + quad*8 + j, n = nt*16 + l16. Start parity is lane-only, so
// per-lane table base is fixed; fragment = 4 consecutive dwords at
// tb[16kt - 8nt + 8 + j] (compiler -> 2x ds_read2_b32). Symmetric for
// A-operand (V pass, nt=mtile) and B-operand (H pass).
__device__ __forceinline__ short8 wbuild2(const int* tb, int nt, int kt) {
  Frag u;
#pragma unroll
  for (int j = 0; j < 4; ++j) u.i[j] = tb[16 * kt - 8 * nt + 8 + j];
  return u.s8;
}

__device__ __forceinline__ void load_xy(const Smem& sm, int row, int quad,
                                        Frag fx[2], Frag fy[2]) {
  const short* px = &sm.mp[0][row * MPS + quad * 8];
  const short* py = &sm.mp[1][row * MPS + quad * 8];
  *(int2*)&fx[0].i[0] = *(const int2*)(px);
  *(int2*)&fx[0].i[2] = *(const int2*)(px + 4);
  *(int2*)&fx[1].i[0] = *(const int2*)(px + 32);
  *(int2*)&fx[1].i[2] = *(const int2*)(px + 36);
  *(int2*)&fy[0].i[0] = *(const int2*)(py);
  *(int2*)&fy[0].i[2] = *(const int2*)(py + 4);
  *(int2*)&fy[1].i[0] = *(const int2*)(py + 32);
  *(int2*)&fy[1].i[2] = *(const int2*)(py + 36);
}

__global__ __launch_bounds__(256, 2) void msssim_l1_kernel(
    const float* __restrict__ x, const float* __restrict__ y,
    const float* __restrict__ gm, float* __restrict__ out) {
  __shared__ Smem sm;
  const int tid = threadIdx.x;
  const int lane = tid & 63;
  const int w = tid >> 6;
  const int quad = lane >> 4;
  const int l16 = lane & 15;

  // corr: fp32/bf16 tap-sum compensation for the l1 conv (sigma 4)
  float corr;
  {
    float traw4 = (lane < 33) ? gm[4 * 1089 + 528 + lane] : 0.f;
    float g = traw4 * rsqrtf(__shfl(traw4, 16, 64));
    float se = g, st = bfl(f2bf(g));
#pragma unroll
    for (int off = 32; off > 0; off >>= 1) {
      se += __shfl_xor(se, off, 64);
      st += __shfl_xor(st, off, 64);
    }
    float r1 = se / st;
    corr = r1 * r1;
  }

  // build dual-parity tap tables (480 dwords; gm is L2-hot)
  {
    int* gt = &sm.gtab[0][0][0];
    for (int q = tid; q < 480; q += 256) {
      int par = q >= 240;
      int rem = par ? q - 240 : q;
      int s = rem / 48;
      int i = rem - s * 48;
      int t0 = 2 * i + par;
      const float* grow = gm + s * 1089 + 528;
      float rsc = rsqrtf(grow[16]);
      int g0 = t0 - 31, g1 = t0 - 30;
      unsigned lo = (g0 >= 0 && g0 <= 32) ? f2bf(grow[g0] * rsc) : 0u;
      unsigned hi = (g1 >= 0 && g1 <= 32) ? f2bf(grow[g1] * rsc) : 0u;
      gt[q] = (int)(lo | (hi << 16));
    }
  }

  // per-lane table base: parity of start = (l16+1)&1; bias -8 keeps all
  // wbuild2 immediate offsets non-negative
  const int D = (quad * 8 - l16 + 31) >> 1;
  const int* gD = &sm.gtab[(l16 & 1) ? 0 : 1][0][0] + D - 8;

  // 64x64 halo patch, zero-padded; bf16 x/y maps in LDS (mp region)
  const float* xb = x + blockIdx.z * (512 * 512);
  const float* yb = y + blockIdx.z * (512 * 512);
  const int rb = blockIdx.y * 32 - 16;
  const int cb = blockIdx.x * 32 - 16;
  for (int f = tid; f < 1024; f += 256) {
    int pr = f >> 4;
    int pc = (f & 15) << 2;
    int gr = rb + pr, gc = cb + pc;
    float4 vx = make_float4(0.f, 0.f, 0.f, 0.f);
    float4 vy = vx;
    if (gr >= 0 && gr < 512 && gc >= 0 && gc < 512) {
      vx = *(const float4*)(xb + gr * 512 + gc);
      vy = *(const float4*)(yb + gr * 512 + gc);
    }
    const int base = pr * MPS + pc;
    *(int2*)(&sm.mp[0][base]) =
        make_int2((int)pk(vx.x, vx.y), (int)pk(vx.z, vx.w));
    *(int2*)(&sm.mp[1][base]) =
        make_int2((int)pk(vy.x, vy.y), (int)pk(vy.z, vy.w));
  }
  __syncthreads();  // B1: patch + tables ready

  // persistent A-fragments for THIS wave's map (m = w), all 4 row tiles;
  // every wave also builds |x-y| fragments for ITS OWN mtile (mt == w)
  Frag A[4][2];
  Frag dA[2];
#pragma unroll
  for (int mt = 0; mt < 4; ++mt) {
    Frag fx[2], fy[2];
    load_xy(sm, mt * 16 + l16, quad, fx, fy);
    if (mt == w) {  // own-mtile |x-y| fragments (plane 4, balanced)
#pragma unroll
      for (int h = 0; h < 2; ++h)
#pragma unroll
        for (int i = 0; i < 4; ++i) {
          unsigned ux = (unsigned)fx[h].i[i], uy = (unsigned)fy[h].i[i];
          dA[h].i[i] =
              (int)pk(fabsf(bfl(ux) - bfl(uy)), fabsf(bfh(ux) - bfh(uy)));
        }
    }
    if (w == 0) {
      A[mt][0] = fx[0];
      A[mt][1] = fx[1];
    } else if (w == 1) {
      A[mt][0] = fy[0];
      A[mt][1] = fy[1];
    } else {
#pragma unroll
      for (int h = 0; h < 2; ++h)
#pragma unroll
        for (int i = 0; i < 4; ++i) {
          unsigned ux = (unsigned)fx[h].i[i], uy = (unsigned)fy[h].i[i];
          float xl = bfl(ux), xh = bfh(ux), yl = bfl(uy), yh = bfh(uy);
          A[mt][h].i[i] = (w == 2) ? (int)pk(fmaf(xl, xl, yl * yl),
                                            fmaf(xh, xh, yh * yh))
                                   : (int)pk(xl * yl, xh * yh);
        }
    }
  }
  __syncthreads();  // B2: all mp reads done -> hbT may overwrite the union

  const int mtv = w >> 1, ntv = w & 1;
  f32x4 Pcs = {1.f, 1.f, 1.f, 1.f};
  f32x4 lumP = {0.f, 0.f, 0.f, 0.f};
  f32x4 l1v = {0.f, 0.f, 0.f, 0.f};

  // ============ groups {0,1} and {2,3}: 4-map sigmas, 8 planes ============
#pragma unroll
  for (int gidx = 0; gidx < 2; ++gidx) {
    const int s0 = gidx * 2;
#pragma unroll
    for (int ds = 0; ds < 2; ++ds) {  // H: wave w = map w, plane ds*4+w
      const int s = s0 + ds;
      const int* tb = gD + s * 48;
      short8 wf[2][2];
#pragma unroll
      for (int nt = 0; nt < 2; ++nt)
#pragma unroll
        for (int kt = 0; kt < 2; ++kt) wf[nt][kt] = wbuild2(tb, nt, kt);
#pragma unroll
      for (int mt = 0; mt < 4; ++mt)
#pragma unroll
        for (int nt = 0; nt < 2; ++nt) {
          f32x4 acc = {0.f, 0.f, 0.f, 0.f};
          acc = __builtin_amdgcn_mfma_f32_16x16x32_bf16(A[mt][0].s8, wf[nt][0],
                                                        acc, 0, 0, 0);
          acc = __builtin_amdgcn_mfma_f32_16x16x32_bf16(A[mt][1].s8, wf[nt][1],
                                                        acc, 0, 0, 0);
          *(int2*)(&sm.hbT[ds * 4 + w][(nt * 16 + l16) * HTS + mt * 16 +
                                       quad * 4]) =
              make_int2((int)pk(acc[0], acc[1]), (int)pk(acc[2], acc[3]));
        }
    }
    __syncthreads();  // group hbT ready

#pragma unroll
    for (int ds = 0; ds < 2; ++ds) {  // V + combine: wave = output quadrant
      const int s = s0 + ds;
      const int* tb = gD + s * 48;
      short8 wa0 = wbuild2(tb, mtv, 0);
      short8 wa1 = wbuild2(tb, mtv, 1);
      f32x4 va[4];
#pragma unroll
      for (int m = 0; m < 4; ++m) {
        const short* bp =
            &sm.hbT[ds * 4 + m][(ntv * 16 + l16) * HTS + quad * 8];
        Frag b0, b1;
        *(int2*)&b0.i[0] = *(const int2*)(bp);
        *(int2*)&b0.i[2] = *(const int2*)(bp + 4);
        *(int2*)&b1.i[0] = *(const int2*)(bp + 32);
        *(int2*)&b1.i[2] = *(const int2*)(bp + 36);
        f32x4 acc = {0.f, 0.f, 0.f, 0.f};
        acc = __builtin_amdgcn_mfma_f32_16x16x32_bf16(wa0, b0.s8, acc, 0, 0,
                                                      0);
        acc = __builtin_amdgcn_mfma_f32_16x16x32_bf16(wa1, b1.s8, acc, 0, 0,
                                                      0);
        va[m] = acc;
      }
#pragma unroll
      for (int r = 0; r < 4; ++r) {
        float mux = va[0][r], muy = va[1][r], m2 = va[2][r], mxy = va[3][r];
        float cs = (2.f * (mxy - mux * muy) + kC2) *
                   frcp((m2 - mux * mux - muy * muy) + kC2);
        Pcs[r] *= cs;
      }
    }
    __syncthreads();  // group V reads done, hbT reusable
  }

  // ================= group {4}: 4 maps + |x-y| (5 planes) =================
  {
    const int* tb = gD + 4 * 48;
    short8 wf[2][2];
#pragma unroll
    for (int nt = 0; nt < 2; ++nt)
#pragma unroll
      for (int kt = 0; kt < 2; ++kt) wf[nt][kt] = wbuild2(tb, nt, kt);
#pragma unroll
    for (int mt = 0; mt < 4; ++mt)
#pragma unroll
      for (int nt = 0; nt < 2; ++nt) {
        f32x4 acc = {0.f, 0.f, 0.f, 0.f};
        acc = __builtin_amdgcn_mfma_f32_16x16x32_bf16(A[mt][0].s8, wf[nt][0],
                                                      acc, 0, 0, 0);
        acc = __builtin_amdgcn_mfma_f32_16x16x32_bf16(A[mt][1].s8, wf[nt][1],
                                                      acc, 0, 0, 0);
        *(int2*)(&sm.hbT[w][(nt * 16 + l16) * HTS + mt * 16 + quad * 4]) =
            make_int2((int)pk(acc[0], acc[1]), (int)pk(acc[2], acc[3]));
      }
    // plane 4 (|x-y|): each wave computes ITS mtile (= w)
#pragma unroll
    for (int nt = 0; nt < 2; ++nt) {
      f32x4 acc = {0.f, 0.f, 0.f, 0.f};
      acc = __builtin_amdgcn_mfma_f32_16x16x32_bf16(dA[0].s8, wf[nt][0], acc,
                                                    0, 0, 0);
      acc = __builtin_amdgcn_mfma_f32_16x16x32_bf16(dA[1].s8, wf[nt][1], acc,
                                                    0, 0, 0);
      *(int2*)(&sm.hbT[4][(nt * 16 + l16) * HTS + w * 16 + quad * 4]) =
          make_int2((int)pk(acc[0], acc[1]), (int)pk(acc[2], acc[3]));
    }
    __syncthreads();  // sigma-4 hbT ready

    short8 wa0 = wbuild2(tb, mtv, 0);
    short8 wa1 = wbuild2(tb, mtv, 1);
    f32x4 va[5];
#pragma unroll
    for (int m = 0; m < 5; ++m) {
      const short* bp = &sm.hbT[m][(ntv * 16 + l16) * HTS + quad * 8];
      Frag b0, b1;
      *(int2*)&b0.i[0] = *(const int2*)(bp);
      *(int2*)&b0.i[2] = *(const int2*)(bp + 4);
      *(int2*)&b1.i[0] = *(const int2*)(bp + 32);
      *(int2*)&b1.i[2] = *(const int2*)(bp + 36);
      f32x4 acc = {0.f, 0.f, 0.f, 0.f};
      acc = __builtin_amdgcn_mfma_f32_16x16x32_bf16(wa0, b0.s8, acc, 0, 0, 0);
      acc = __builtin_amdgcn_mfma_f32_16x16x32_bf16(wa1, b1.s8, acc, 0, 0, 0);
      va[m] = acc;
    }
#pragma unroll
    for (int r = 0; r < 4; ++r) {
      float mux = va[0][r], muy = va[1][r], m2 = va[2][r], mxy = va[3][r];
      float mux2 = mux * mux, muy2 = muy * muy, muxy = mux * muy;
      float cs = (2.f * (mxy - muxy) + kC2) * frcp((m2 - mux2 - muy2) + kC2);
      Pcs[r] *= cs;
      lumP[r] = ((2.f * muxy + kC1) * frcp(mux2 + muy2 + kC1)) * Pcs[r];
      l1v[r] = va[4][r] * corr;
    }
  }

  // loss_mix = alpha*(1 - lum*PIcs) + (1-alpha)*gaussian_l1 ; out = 20*mean
  float lsum = 0.f;
#pragma unroll
  for (int r = 0; r < 4; ++r)
    lsum += kAlpha * (1.f - lumP[r]) + (1.f - kAlpha) * l1v[r];
#pragma unroll
  for (int off = 32; off > 0; off >>= 1) lsum += __shfl_down(lsum, off, 64);
  if ((tid & 63) == 0) sm.red[tid >> 6] = lsum;
  __syncthreads();
  if (tid == 0) {
    float t = sm.red[0] + sm.red[1] + sm.red[2] + sm.red[3];
    atomicAdd(out, t * (20.f / (16.f * 512.f * 512.f)));
  }
}

}  // namespace

extern "C" void kernel_launch(void* const* d_in, const int* in_sizes, int n_in,
                              void* d_out, int out_size, void* d_ws,
                              size_t ws_size, hipStream_t stream) {
  (void)in_sizes;
  (void)n_in;
  (void)d_ws;
  (void)ws_size;
  (void)out_size;
  const float* x = (const float*)d_in[0];
  const float* y = (const float*)d_in[1];
  const float* gm = (const float*)d_in[2];
  float* out = (float*)d_out;
  hipMemsetAsync(out, 0, sizeof(float), stream);
  dim3 grid(16, 16, 16);
  msssim_l1_kernel<<<grid, dim3(256), 0, stream>>>(x, y, gm, out);
}